// Round 1
// baseline (403.285 us; speedup 1.0000x reference)
//
#include <hip/hip_runtime.h>

#define NT 128
#define RROWS 45          // output rows per block (multiple of 9!)
#define STRIP 256         // output cols per block (2 per thread)
#define PW 264            // staged (x,y) pairs per row: STRIP + 8 halo
#define WID 1024
#define HEI 1024
#define OWD 1016          // valid conv output dim (1024 - 8)

struct H10 { float v[10]; };   // 5 channels x 2 columns of horizontal-conv results

__global__ __launch_bounds__(NT, 3)
void ssim_main(const float* __restrict__ X, const float* __restrict__ Y,
               const float* __restrict__ Wg, double* __restrict__ acc)
{
    __shared__ float2 P2[2][PW];     // double-buffered interleaved row: P2[s][c] = (x_c, y_c)
    __shared__ float  wsum[2][2];

    const int t  = threadIdx.x;
    const int r0 = blockIdx.x * RROWS;          // 45*rb, multiple of 9
    const int c0 = blockIdx.y * STRIP;
    const size_t ibase = (size_t)blockIdx.z * (size_t)(WID * HEI);
    const bool halo_t = (t < 4) && (c0 + STRIP < WID);

    // 1D gaussian from row 4 of w2d: w2d[4][k] = g4*g[k], row sum = g4
    float g[9];
    {
        float s = 0.f;
#pragma unroll
        for (int k = 0; k < 9; ++k) { g[k] = Wg[36 + k]; s += g[k]; }
        float rs = __builtin_amdgcn_rcpf(s);
#pragma unroll
        for (int k = 0; k < 9; ++k) g[k] *= rs;
    }

    const float C1 = 0.0004f, C2 = 0.0036f;
    float ssim_acc = 0.f, l1_acc = 0.f;

    H10 hr[9];   // register ring of horizontal conv rows (static indices after unroll)

    const float2* __restrict__ Xp = (const float2*)(X + ibase + c0);
    const float2* __restrict__ Yp = (const float2*)(Y + ibase + c0);

    float2 cx, cy, cxh, cyh;   // prefetched row (this thread's pair + halo pair)

    auto preload = [&](int row) {
        if (row < HEI) {
            const float2* xr = Xp + (size_t)row * (WID / 2);
            const float2* yr = Yp + (size_t)row * (WID / 2);
            cx = xr[t]; cy = yr[t];
            if (halo_t) { cxh = xr[128 + t]; cyh = yr[128 + t]; }
        }
    };
    auto store_cur = [&](int row, int slot, bool owned) {
        if (row < HEI) {
            float4* dst = (float4*)&P2[slot][0];           // F4[i] = (x_{2i}, y_{2i}, x_{2i+1}, y_{2i+1})
            dst[t] = make_float4(cx.x, cy.x, cx.y, cy.y);
            if (halo_t) dst[128 + t] = make_float4(cxh.x, cyh.x, cxh.y, cyh.y);
            if (owned) l1_acc += fabsf(cx.x - cy.x) + fabsf(cx.y - cy.y);
        }
    };

    // horizontal 9-tap conv of 5 channels for both columns, from LDS slot
    auto hcomp = [&](int slot) -> H10 {
        const float4* src = (const float4*)&P2[slot][0];
        float4 f0 = src[t], f1 = src[t + 1], f2 = src[t + 2], f3 = src[t + 3], f4 = src[t + 4];
        float px[10] = { f0.x, f0.z, f1.x, f1.z, f2.x, f2.z, f3.x, f3.z, f4.x, f4.z };
        float py[10] = { f0.y, f0.w, f1.y, f1.w, f2.y, f2.w, f3.y, f3.w, f4.y, f4.w };
        float xx[10], yy[10], xy[10];
#pragma unroll
        for (int e = 0; e < 10; ++e) { xx[e] = px[e] * px[e]; yy[e] = py[e] * py[e]; xy[e] = px[e] * py[e]; }
        H10 h;
#pragma unroll
        for (int c = 0; c < 10; ++c) h.v[c] = 0.f;
#pragma unroll
        for (int k = 0; k < 9; ++k) {
            const float gk = g[k];
            h.v[0] = fmaf(gk, px[k],     h.v[0]);
            h.v[1] = fmaf(gk, py[k],     h.v[1]);
            h.v[2] = fmaf(gk, xx[k],     h.v[2]);
            h.v[3] = fmaf(gk, yy[k],     h.v[3]);
            h.v[4] = fmaf(gk, xy[k],     h.v[4]);
            h.v[5] = fmaf(gk, px[k + 1], h.v[5]);
            h.v[6] = fmaf(gk, py[k + 1], h.v[6]);
            h.v[7] = fmaf(gk, xx[k + 1], h.v[7]);
            h.v[8] = fmaf(gk, yy[k + 1], h.v[8]);
            h.v[9] = fmaf(gk, xy[k + 1], h.v[9]);
        }
        return h;
    };

    auto ssim_one = [&](float ux, float uy, float uxx, float uyy, float uxy) -> float {
        float uxux = ux * ux, uyuy = uy * uy, uxuy = ux * uy;
        float vx = uxx - uxux, vy = uyy - uyuy, vxy = uxy - uxuy;
        float A1 = 2.f * uxuy + C1;
        float A2 = 2.f * vxy + C2;
        float B1 = uxux + uyuy + C1;
        float B2 = vx + vy + C2;
        return (A1 * A2) * __builtin_amdgcn_rcpf(B1 * B2);
    };

    // ---- prologue: rows r0..r0+7 -> ring slots 0..7 (row ≡ slot mod 9 since r0 % 9 == 0)
#pragma unroll
    for (int i = 0; i < 8; ++i) {
        preload(r0 + i);
        store_cur(r0 + i, i & 1, true);
        __syncthreads();
        hr[i] = hcomp(i & 1);
    }
    preload(r0 + 8);

    const int col0 = c0 + 2 * t;
    const bool vA = (col0 < OWD);
    const bool vB = (col0 + 1 < OWD);

#pragma unroll 1
    for (int jb = 0; jb < RROWS / 9; ++jb) {
#pragma unroll
        for (int ju = 0; ju < 9; ++ju) {
            const int j = jb * 9 + ju;
            const int rnew = r0 + j + 8;
            store_cur(rnew, (j + 8) & 1, (j + 8) < RROWS);     // stage row j+8; L1 on owned rows
            __syncthreads();
            if (j < RROWS - 1) preload(rnew + 1);              // prefetch next row (post-barrier)
            if (r0 + j < OWD) {                                 // uniform guard
                hr[(ju + 8) % 9] = hcomp((j + 8) & 1);
                float u[10];
#pragma unroll
                for (int c = 0; c < 10; ++c) u[c] = 0.f;
#pragma unroll
                for (int k = 0; k < 9; ++k) {
                    const float gk = g[k];
                    const float* hv = hr[(ju + k) % 9].v;
#pragma unroll
                    for (int c = 0; c < 10; ++c) u[c] = fmaf(gk, hv[c], u[c]);
                }
                float SA = ssim_one(u[0], u[1], u[2], u[3], u[4]);
                float SB = ssim_one(u[5], u[6], u[7], u[8], u[9]);
                ssim_acc += vA ? SA : 0.f;
                ssim_acc += vB ? SB : 0.f;
            }
        }
    }

    // ---- reduction: wave shfl -> LDS -> one double atomic per block
#pragma unroll
    for (int off = 32; off > 0; off >>= 1) {
        ssim_acc += __shfl_down(ssim_acc, off);
        l1_acc   += __shfl_down(l1_acc, off);
    }
    const int wid = t >> 6;
    if ((t & 63) == 0) { wsum[wid][0] = ssim_acc; wsum[wid][1] = l1_acc; }
    __syncthreads();
    if (t == 0) {
        double s = (double)wsum[0][0] + (double)wsum[1][0];
        double l = (double)wsum[0][1] + (double)wsum[1][1];
        atomicAdd(acc + 0, s);
        atomicAdd(acc + 1, l);
    }
}

__global__ void ssim_final(const double* __restrict__ acc, float* __restrict__ out)
{
    const double n_ssim = 33032192.0;   // 32*1016*1016
    const double n_l1   = 33554432.0;   // 32*1024*1024
    double ssim_loss = 1.0 - acc[0] / n_ssim;
    double l1        = acc[1] / n_l1;
    out[0] = (float)(0.5 * ssim_loss + 1.0 * l1);
}

extern "C" void kernel_launch(void* const* d_in, const int* in_sizes, int n_in,
                              void* d_out, int out_size, void* d_ws, size_t ws_size,
                              hipStream_t stream)
{
    const float* X  = (const float*)d_in[0];
    const float* Y  = (const float*)d_in[1];
    const float* Wg = (const float*)d_in[2];
    float*  out = (float*)d_out;
    double* acc = (double*)d_ws;

    hipMemsetAsync(acc, 0, 2 * sizeof(double), stream);
    dim3 grid(23, 4, 32);   // rowblocks(ceil(1016/45)) x col-strips x images
    ssim_main<<<grid, NT, 0, stream>>>(X, Y, Wg, acc);
    ssim_final<<<1, 1, 0, stream>>>(acc, out);
}